// Round 3
// baseline (16383.557 us; speedup 1.0000x reference)
//
#include <hip/hip_runtime.h>

// DKVMN fused forward, round 3 — single kernel.
// grid = B = 256 blocks x 1024 threads (16 waves). State (B*N*DV fp32 = 128 MB)
// streams through d_ws; U=16 timesteps applied per pass (32 passes) to halve
// state traffic vs R2. Erase/add gates computed in-kernel, batched 32 steps
// (SU=32) per "super-pass" with 8 accumulators/thread (fits registers — R2's
// separate gates kernel used 32/thread and spilled 41 GB of scratch traffic).
// s_v (interaction embeds) aliases s_w (logits) — disjoint live ranges.
// LDS: w/v 32K + e 32K + a 32K + q 4K + r 16K + h1 4K = 120 KB, 1 block/CU.

#define B_ 256
#define T_ 512
#define N_ 512
#define DK_ 64
#define DV_ 256
#define S_ 64
#define U_ 16                       // timesteps per stream pass
#define SU_ 32                      // timesteps per gate batch (super-pass)
#define NTB 1024
#define NSUPER (T_ / SU_)           // 16
#define PPS (SU_ / U_)              // 2 passes per super-pass

__device__ __forceinline__ float dot4(float4 a, float4 b) {
  return a.x * b.x + a.y * b.y + a.z * b.z + a.w * b.w;
}

__global__ __launch_bounds__(NTB, 1) void dkvmn_fused(
    const int* __restrict__ concepts, const int* __restrict__ interactions,
    const float* __restrict__ Kmem, const float* __restrict__ Vmem,
    const float* __restrict__ cemb, const float* __restrict__ iemb,
    const float* __restrict__ We, const float* __restrict__ be,
    const float* __restrict__ Wa, const float* __restrict__ ba,
    const float* __restrict__ W1, const float* __restrict__ b1,
    const float* __restrict__ W2, const float* __restrict__ b2,
    const float* __restrict__ W3, const float* __restrict__ b3,
    float* __restrict__ out, float* __restrict__ state) {
  __shared__ float s_w[U_][N_];    // 32 KB; aliased as v[SU_][DV_] in gate phase
  __shared__ float s_e[SU_][DV_];  // 32 KB
  __shared__ float s_a[SU_][DV_];  // 32 KB
  __shared__ float s_q[U_][DK_];   // 4 KB
  __shared__ float s_r[U_][DV_];   // 16 KB
  __shared__ float s_h1[U_][S_];   // 4 KB
  float* s_v = &s_w[0][0];         // alias: v dead once logits start writing s_w

  const int tid = threadIdx.x;
  const int b = blockIdx.x;
  const int lane = tid & 63;
  const int wid = tid >> 6;  // 16 waves
  float4* stb4 = (float4*)state + (size_t)b * (N_ * DV_ / 4);

  for (int sp = 0; sp < NSUPER; ++sp) {
    const int s0 = sp * SU_;

    // ---- stage v: interaction embeds for 32 steps (into s_w alias) ----
    // safe: last s_w readers (prev pass stream/softmax) are behind barrier E.
    for (int idx = tid; idx < SU_ * DV_; idx += NTB) {
      const int u32 = idx >> 8, d = idx & (DV_ - 1);
      const int iv = interactions[b * T_ + s0 + u32];
      s_v[u32 * DV_ + d] = iv ? iemb[iv * DV_ + d] : 0.f;
    }
    __syncthreads();  // G: v staged before gates read it

    // ---- gates for 32 steps: thread owns (d, 8 u's); 16 accumulators ----
    {
      const int d = tid & (DV_ - 1), ug = tid >> 8;  // ug in 0..3
      float accE[8], accA[8];
#pragma unroll
      for (int j = 0; j < 8; ++j) { accE[j] = 0.f; accA[j] = 0.f; }
      const float4* We4 = (const float4*)(We + d * DV_);
      const float4* Wa4 = (const float4*)(Wa + d * DV_);
      for (int kk = 0; kk < DV_ / 4; ++kk) {
        const float4 we = We4[kk], wa = Wa4[kk];
#pragma unroll
        for (int j = 0; j < 8; ++j) {
          const float4 v4 = *(const float4*)&s_v[(ug * 8 + j) * DV_ + kk * 4];
          accE[j] += dot4(we, v4);
          accA[j] += dot4(wa, v4);
        }
      }
      const float bed = be[d], bad = ba[d];
#pragma unroll
      for (int j = 0; j < 8; ++j) {
        s_e[ug * 8 + j][d] = 1.f / (1.f + expf(-(accE[j] + bed)));
        s_a[ug * 8 + j][d] = tanhf(accA[j] + bad);
      }
    }
    // no barrier here: barriers A..D of pass 0 order gate-writes before stream.

    for (int p = 0; p < PPS; ++p) {
      const int gp = sp * PPS + p;   // global pass id
      const int t0 = s0 + p * U_;
      const int ub = p * U_;         // base row into s_e/s_a
      __syncthreads();  // A: prev MLP done with s_r/s_q/s_h1; gates done (p==0)

      // ---- stage q: one element per thread (16x64 = 1024) ----
      {
        const int c = concepts[b * T_ + t0 + wid];
        s_q[wid][lane] = c ? cemb[c * DK_ + lane] : 0.f;
      }
      __syncthreads();  // B

      // ---- logits: n = tid&511, 8 u's per thread ----
      {
        const int n = tid & (N_ - 1), ug = tid >> 9;  // ug in 0..1
        const float4* kr = (const float4*)(Kmem + n * DK_);
        float acc[8];
#pragma unroll
        for (int j = 0; j < 8; ++j) acc[j] = 0.f;
#pragma unroll
        for (int kk = 0; kk < DK_ / 4; ++kk) {
          const float4 k4 = kr[kk];
#pragma unroll
          for (int j = 0; j < 8; ++j)
            acc[j] += dot4(k4, *(const float4*)&s_q[ug * 8 + j][kk * 4]);
        }
#pragma unroll
        for (int j = 0; j < 8; ++j) s_w[ug * 8 + j][n] = acc[j];
      }
      __syncthreads();  // C

      // ---- softmax (wave wid owns u=wid) + zero s_r ----
      {
        *(float4*)&s_r[wid][lane * 4] = make_float4(0.f, 0.f, 0.f, 0.f);
        const int u = wid;
        float lg[8], mx = -1e30f;
#pragma unroll
        for (int k = 0; k < 8; ++k) {
          lg[k] = s_w[u][lane + 64 * k];
          mx = fmaxf(mx, lg[k]);
        }
        for (int off = 32; off > 0; off >>= 1) mx = fmaxf(mx, __shfl_xor(mx, off, 64));
        float sum = 0.f;
#pragma unroll
        for (int k = 0; k < 8; ++k) {
          lg[k] = expf(lg[k] - mx);
          sum += lg[k];
        }
        for (int off = 32; off > 0; off >>= 1) sum += __shfl_xor(sum, off, 64);
        const float inv = 1.f / sum;
#pragma unroll
        for (int k = 0; k < 8; ++k) s_w[u][lane + 64 * k] = lg[k] * inv;
      }
      __syncthreads();  // D

      // ---- stream: wave owns 32 rows; 2-row chunks, 1-chunk lookahead ----
      {
        const int d4 = lane;
        float4 racc[U_];
#pragma unroll
        for (int u = 0; u < U_; ++u) racc[u] = make_float4(0.f, 0.f, 0.f, 0.f);
        const float4* src = gp ? (const float4*)stb4 : (const float4*)Vmem;
        const int n0 = wid * 32;
        float4 mA = src[(n0 + 0) * (DV_ / 4) + d4];
        float4 mB = src[(n0 + 1) * (DV_ / 4) + d4];
        for (int c = 0; c < 32; c += 2) {
          float4 nxA, nxB;
          const bool more = (c + 2) < 32;
          if (more) {
            nxA = src[(n0 + c + 2) * (DV_ / 4) + d4];
            nxB = src[(n0 + c + 3) * (DV_ / 4) + d4];
          }
          const int na = n0 + c, nb = na + 1;
#pragma unroll
          for (int u = 0; u < U_; ++u) {
            const float w0 = s_w[u][na], w1 = s_w[u][nb];
            const float4 eu = *(const float4*)&s_e[ub + u][d4 * 4];
            const float4 au = *(const float4*)&s_a[ub + u][d4 * 4];
            racc[u].x = fmaf(w0, mA.x, racc[u].x);
            racc[u].y = fmaf(w0, mA.y, racc[u].y);
            racc[u].z = fmaf(w0, mA.z, racc[u].z);
            racc[u].w = fmaf(w0, mA.w, racc[u].w);
            mA.x = fmaf(-w0, fmaf(eu.x, mA.x, -au.x), mA.x);
            mA.y = fmaf(-w0, fmaf(eu.y, mA.y, -au.y), mA.y);
            mA.z = fmaf(-w0, fmaf(eu.z, mA.z, -au.z), mA.z);
            mA.w = fmaf(-w0, fmaf(eu.w, mA.w, -au.w), mA.w);
            racc[u].x = fmaf(w1, mB.x, racc[u].x);
            racc[u].y = fmaf(w1, mB.y, racc[u].y);
            racc[u].z = fmaf(w1, mB.z, racc[u].z);
            racc[u].w = fmaf(w1, mB.w, racc[u].w);
            mB.x = fmaf(-w1, fmaf(eu.x, mB.x, -au.x), mB.x);
            mB.y = fmaf(-w1, fmaf(eu.y, mB.y, -au.y), mB.y);
            mB.z = fmaf(-w1, fmaf(eu.z, mB.z, -au.z), mB.z);
            mB.w = fmaf(-w1, fmaf(eu.w, mB.w, -au.w), mB.w);
          }
          stb4[na * (DV_ / 4) + d4] = mA;
          stb4[nb * (DV_ / 4) + d4] = mB;
          if (more) { mA = nxA; mB = nxB; }
        }
#pragma unroll
        for (int u = 0; u < U_; ++u) {
          atomicAdd(&s_r[u][d4 * 4 + 0], racc[u].x);
          atomicAdd(&s_r[u][d4 * 4 + 1], racc[u].y);
          atomicAdd(&s_r[u][d4 * 4 + 2], racc[u].z);
          atomicAdd(&s_r[u][d4 * 4 + 3], racc[u].w);
        }
      }
      __syncthreads();  // E

      // ---- MLP layer 1: all 16 waves, wave wid owns u=wid ----
      {
        const int u = wid;
        float acc = b1[lane];
        const float4* w1r = (const float4*)(W1 + lane * (DV_ + DK_));
#pragma unroll
        for (int kk = 0; kk < DV_ / 4; ++kk)
          acc += dot4(w1r[kk], *(const float4*)&s_r[u][kk * 4]);
#pragma unroll
        for (int kk = 0; kk < DK_ / 4; ++kk)
          acc += dot4(w1r[DV_ / 4 + kk], *(const float4*)&s_q[u][kk * 4]);
        s_h1[u][lane] = fmaxf(acc, 0.f);
      }
      __syncthreads();  // F

      // ---- MLP layer 2 + output head (h2 in registers, W3 via shuffle) ----
      {
        const int u = wid;
        float acc = b2[lane];
        const float4* w2r = (const float4*)(W2 + lane * S_);
#pragma unroll
        for (int kk = 0; kk < S_ / 4; ++kk)
          acc += dot4(w2r[kk], *(const float4*)&s_h1[u][kk * 4]);
        float pp = fmaxf(acc, 0.f) * W3[lane];
        for (int off = 32; off > 0; off >>= 1) pp += __shfl_xor(pp, off, 64);
        if (lane == 0)
          out[(size_t)b * T_ + t0 + u] = 1.f / (1.f + expf(-(pp + b3[0])));
      }
    }  // pass
  }    // super-pass
}

extern "C" void kernel_launch(void* const* d_in, const int* in_sizes, int n_in,
                              void* d_out, int out_size, void* d_ws, size_t ws_size,
                              hipStream_t stream) {
  const int* concepts = (const int*)d_in[0];
  const int* interactions = (const int*)d_in[1];
  const float* Kmem = (const float*)d_in[2];
  const float* Vmem = (const float*)d_in[3];
  const float* cemb = (const float*)d_in[4];
  const float* iemb = (const float*)d_in[5];
  const float* We = (const float*)d_in[6];
  const float* be = (const float*)d_in[7];
  const float* Wa = (const float*)d_in[8];
  const float* ba = (const float*)d_in[9];
  const float* W1 = (const float*)d_in[10];
  const float* b1 = (const float*)d_in[11];
  const float* W2 = (const float*)d_in[12];
  const float* b2 = (const float*)d_in[13];
  const float* W3 = (const float*)d_in[14];
  const float* b3 = (const float*)d_in[15];
  float* out = (float*)d_out;
  float* state = (float*)d_ws;  // B*N*DV fp32 = 128 MiB

  dkvmn_fused<<<dim3(B_), dim3(NTB), 0, stream>>>(
      concepts, interactions, Kmem, Vmem, cemb, iemb, We, be, Wa, ba,
      W1, b1, W2, b2, W3, b3, out, state);
}

// Round 4
// 8346.682 us; speedup vs baseline: 1.9629x; 1.9629x over previous
//
#include <hip/hip_runtime.h>

// DKVMN fused forward, round 4.
// grid = B = 256 blocks x 1024 threads (16 waves, 4/SIMD -> HW VGPR cap 128).
// R3 failed because the compiler budgeted 64 VGPRs for a loop needing ~100 ->
// 40 GB scratch spill. Fix: (a) amdgpu_waves_per_eu(4,4) pins the budget at
// 128; (b) U=8 (racc[8]=32 VGPRs) with the state stored as fp16 in d_ws
// (64 MB, L3-resident) -> same 8.2 GB traffic as U=16/fp32, half the regs.
// Gates batched SU=32 steps (8 acc-pairs/thread, W-rows amortized 8x).
// LDS: wv 32K + e 32K + a 32K + q 2K + r 8K + h1 2K = 108 KB, 1 block/CU.

#define B_ 256
#define T_ 512
#define N_ 512
#define DK_ 64
#define DV_ 256
#define S_ 64
#define U_ 8                        // timesteps per stream pass
#define SU_ 32                      // timesteps per gate batch
#define NTB 1024
#define NSUPER (T_ / SU_)           // 16
#define PPS (SU_ / U_)              // 4 passes per super-pass

typedef _Float16 h16;
typedef __attribute__((ext_vector_type(4))) _Float16 half4;

__device__ __forceinline__ float dot4(float4 a, float4 b) {
  return a.x * b.x + a.y * b.y + a.z * b.z + a.w * b.w;
}
__device__ __forceinline__ float4 h2f(half4 h) {
  return make_float4((float)h.x, (float)h.y, (float)h.z, (float)h.w);
}
__device__ __forceinline__ half4 f2h(float4 f) {
  half4 h;
  h.x = (h16)f.x; h.y = (h16)f.y; h.z = (h16)f.z; h.w = (h16)f.w;
  return h;
}

__global__ void __attribute__((amdgpu_flat_work_group_size(NTB, NTB),
                               amdgpu_waves_per_eu(4, 4)))
dkvmn_fused(
    const int* __restrict__ concepts, const int* __restrict__ interactions,
    const float* __restrict__ Kmem, const float* __restrict__ Vmem,
    const float* __restrict__ cemb, const float* __restrict__ iemb,
    const float* __restrict__ We, const float* __restrict__ be,
    const float* __restrict__ Wa, const float* __restrict__ ba,
    const float* __restrict__ W1, const float* __restrict__ b1,
    const float* __restrict__ W2, const float* __restrict__ b2,
    const float* __restrict__ W3, const float* __restrict__ b3,
    float* __restrict__ out, h16* __restrict__ state) {
  __shared__ float s_wv[SU_ * DV_];  // 32 KB: v[32][256] in gate phase,
                                     //        w[8][512] (first 16 KB) in passes
  __shared__ float s_e[SU_][DV_];    // 32 KB
  __shared__ float s_a[SU_][DV_];    // 32 KB
  __shared__ float s_q[U_][DK_];     // 2 KB
  __shared__ float s_r[U_][DV_];     // 8 KB
  __shared__ float s_h1[U_][S_];     // 2 KB
  float (*s_w)[N_] = (float(*)[N_])s_wv;

  const int tid = threadIdx.x;
  const int b = blockIdx.x;
  const int lane = tid & 63;
  const int wid = tid >> 6;  // 16 waves
  half4* stb = (half4*)state + (size_t)b * (N_ * DV_ / 4);

  // ---- init fp16 state from Vmem (own slice; ordered vs readers by barriers) ----
  {
    const float4* vm4 = (const float4*)Vmem;
    for (int idx = tid; idx < N_ * DV_ / 4; idx += NTB)
      stb[idx] = f2h(vm4[idx]);
  }

  for (int sp = 0; sp < NSUPER; ++sp) {
    const int s0 = sp * SU_;
    __syncthreads();  // G0: prev super-pass readers of s_wv/s_e/s_a done

    // ---- stage v: 32 steps of interaction embeds, float4 per thread ----
    {
      const float4* iemb4 = (const float4*)iemb;
      for (int idx = tid; idx < SU_ * (DV_ / 4); idx += NTB) {
        const int u32 = idx >> 6, f = idx & 63;
        const int iv = interactions[b * T_ + s0 + u32];
        *(float4*)&s_wv[u32 * DV_ + f * 4] =
            iv ? iemb4[(size_t)iv * (DV_ / 4) + f] : make_float4(0.f, 0.f, 0.f, 0.f);
      }
    }
    __syncthreads();  // G1: v staged

    // ---- gates for 32 steps: thread owns (d, 8 u's) ----
    {
      const int d = tid & (DV_ - 1), ug = tid >> 8;  // ug in 0..3
      float accE[8], accA[8];
#pragma unroll
      for (int j = 0; j < 8; ++j) { accE[j] = 0.f; accA[j] = 0.f; }
      const float4* We4 = (const float4*)(We + d * DV_);
      const float4* Wa4 = (const float4*)(Wa + d * DV_);
      for (int kk = 0; kk < DV_ / 4; ++kk) {
        const float4 we = We4[kk], wa = Wa4[kk];
#pragma unroll
        for (int j = 0; j < 8; ++j) {
          const float4 v4 = *(const float4*)&s_wv[(ug * 8 + j) * DV_ + kk * 4];
          accE[j] += dot4(we, v4);
          accA[j] += dot4(wa, v4);
        }
      }
      const float bed = be[d], bad = ba[d];
#pragma unroll
      for (int j = 0; j < 8; ++j) {
        s_e[ug * 8 + j][d] = 1.f / (1.f + expf(-(accE[j] + bed)));
        s_a[ug * 8 + j][d] = tanhf(accA[j] + bad);
      }
    }
    // gate writes ordered before stream reads by barriers A..D of pass 0.

    for (int p = 0; p < PPS; ++p) {
      const int t0 = s0 + p * U_;
      const int ub = p * U_;  // base row into s_e/s_a
      __syncthreads();  // A: prev MLP done with s_q/s_r/s_h1; gates done (p==0)

      // ---- stage q (512 elements) ----
      if (tid < U_ * DK_) {
        const int u = tid >> 6, l = tid & 63;
        const int c = concepts[b * T_ + t0 + u];
        s_q[u][l] = c ? cemb[c * DK_ + l] : 0.f;
      }
      __syncthreads();  // B

      // ---- logits: n = tid&511, 4 u's per thread ----
      {
        const int n = tid & (N_ - 1), ug = tid >> 9;  // 0..1
        const float4* kr = (const float4*)(Kmem + n * DK_);
        float acc[4] = {0.f, 0.f, 0.f, 0.f};
#pragma unroll
        for (int kk = 0; kk < DK_ / 4; ++kk) {
          const float4 k4 = kr[kk];
#pragma unroll
          for (int j = 0; j < 4; ++j)
            acc[j] += dot4(k4, *(const float4*)&s_q[ug * 4 + j][kk * 4]);
        }
#pragma unroll
        for (int j = 0; j < 4; ++j) s_w[ug * 4 + j][n] = acc[j];
      }
      __syncthreads();  // C

      // ---- softmax (waves 0-7, u=wid); waves 8-15 zero s_r ----
      if (wid < U_) {
        const int u = wid;
        float lg[8], mx = -1e30f;
#pragma unroll
        for (int k = 0; k < 8; ++k) {
          lg[k] = s_w[u][lane + 64 * k];
          mx = fmaxf(mx, lg[k]);
        }
        for (int off = 32; off > 0; off >>= 1) mx = fmaxf(mx, __shfl_xor(mx, off, 64));
        float sum = 0.f;
#pragma unroll
        for (int k = 0; k < 8; ++k) {
          lg[k] = expf(lg[k] - mx);
          sum += lg[k];
        }
        for (int off = 32; off > 0; off >>= 1) sum += __shfl_xor(sum, off, 64);
        const float inv = 1.f / sum;
#pragma unroll
        for (int k = 0; k < 8; ++k) s_w[u][lane + 64 * k] = lg[k] * inv;
      } else {
        *(float4*)&s_r[wid - 8][lane * 4] = make_float4(0.f, 0.f, 0.f, 0.f);
      }
      __syncthreads();  // D

      // ---- stream: wave owns 32 rows, fp16 state, 2-row chunks + lookahead ----
      {
        const int d4 = lane;
        float4 racc[U_];
#pragma unroll
        for (int u = 0; u < U_; ++u) racc[u] = make_float4(0.f, 0.f, 0.f, 0.f);
        const int n0 = wid * 32;
        half4 hA = stb[(n0 + 0) * (DV_ / 4) + d4];
        half4 hB = stb[(n0 + 1) * (DV_ / 4) + d4];
        for (int c = 0; c < 32; c += 2) {
          half4 nxA, nxB;
          const bool more = (c + 2) < 32;
          if (more) {
            nxA = stb[(n0 + c + 2) * (DV_ / 4) + d4];
            nxB = stb[(n0 + c + 3) * (DV_ / 4) + d4];
          }
          float4 mA = h2f(hA), mB = h2f(hB);
          const int na = n0 + c, nb = na + 1;
#pragma unroll
          for (int u = 0; u < U_; ++u) {
            const float w0 = s_w[u][na], w1 = s_w[u][nb];
            const float4 eu = *(const float4*)&s_e[ub + u][d4 * 4];
            const float4 au = *(const float4*)&s_a[ub + u][d4 * 4];
            racc[u].x = fmaf(w0, mA.x, racc[u].x);
            racc[u].y = fmaf(w0, mA.y, racc[u].y);
            racc[u].z = fmaf(w0, mA.z, racc[u].z);
            racc[u].w = fmaf(w0, mA.w, racc[u].w);
            mA.x = fmaf(-w0, fmaf(eu.x, mA.x, -au.x), mA.x);
            mA.y = fmaf(-w0, fmaf(eu.y, mA.y, -au.y), mA.y);
            mA.z = fmaf(-w0, fmaf(eu.z, mA.z, -au.z), mA.z);
            mA.w = fmaf(-w0, fmaf(eu.w, mA.w, -au.w), mA.w);
            racc[u].x = fmaf(w1, mB.x, racc[u].x);
            racc[u].y = fmaf(w1, mB.y, racc[u].y);
            racc[u].z = fmaf(w1, mB.z, racc[u].z);
            racc[u].w = fmaf(w1, mB.w, racc[u].w);
            mB.x = fmaf(-w1, fmaf(eu.x, mB.x, -au.x), mB.x);
            mB.y = fmaf(-w1, fmaf(eu.y, mB.y, -au.y), mB.y);
            mB.z = fmaf(-w1, fmaf(eu.z, mB.z, -au.z), mB.z);
            mB.w = fmaf(-w1, fmaf(eu.w, mB.w, -au.w), mB.w);
          }
          stb[na * (DV_ / 4) + d4] = f2h(mA);
          stb[nb * (DV_ / 4) + d4] = f2h(mB);
          if (more) { hA = nxA; hB = nxB; }
        }
#pragma unroll
        for (int u = 0; u < U_; ++u) {
          atomicAdd(&s_r[u][d4 * 4 + 0], racc[u].x);
          atomicAdd(&s_r[u][d4 * 4 + 1], racc[u].y);
          atomicAdd(&s_r[u][d4 * 4 + 2], racc[u].z);
          atomicAdd(&s_r[u][d4 * 4 + 3], racc[u].w);
        }
      }
      __syncthreads();  // E

      // ---- MLP layer 1 (waves 0-7, u=wid) ----
      if (tid < U_ * 64) {
        const int u = wid;
        float acc = b1[lane];
        const float4* w1r = (const float4*)(W1 + lane * (DV_ + DK_));
#pragma unroll
        for (int kk = 0; kk < DV_ / 4; ++kk)
          acc += dot4(w1r[kk], *(const float4*)&s_r[u][kk * 4]);
#pragma unroll
        for (int kk = 0; kk < DK_ / 4; ++kk)
          acc += dot4(w1r[DV_ / 4 + kk], *(const float4*)&s_q[u][kk * 4]);
        s_h1[u][lane] = fmaxf(acc, 0.f);
      }
      __syncthreads();  // F

      // ---- MLP layer 2 + head ----
      if (tid < U_ * 64) {
        const int u = wid;
        float acc = b2[lane];
        const float4* w2r = (const float4*)(W2 + lane * S_);
#pragma unroll
        for (int kk = 0; kk < S_ / 4; ++kk)
          acc += dot4(w2r[kk], *(const float4*)&s_h1[u][kk * 4]);
        float pp = fmaxf(acc, 0.f) * W3[lane];
        for (int off = 32; off > 0; off >>= 1) pp += __shfl_xor(pp, off, 64);
        if (lane == 0)
          out[(size_t)b * T_ + t0 + u] = 1.f / (1.f + expf(-(pp + b3[0])));
      }
    }  // pass
  }    // super-pass
}

extern "C" void kernel_launch(void* const* d_in, const int* in_sizes, int n_in,
                              void* d_out, int out_size, void* d_ws, size_t ws_size,
                              hipStream_t stream) {
  const int* concepts = (const int*)d_in[0];
  const int* interactions = (const int*)d_in[1];
  const float* Kmem = (const float*)d_in[2];
  const float* Vmem = (const float*)d_in[3];
  const float* cemb = (const float*)d_in[4];
  const float* iemb = (const float*)d_in[5];
  const float* We = (const float*)d_in[6];
  const float* be = (const float*)d_in[7];
  const float* Wa = (const float*)d_in[8];
  const float* ba = (const float*)d_in[9];
  const float* W1 = (const float*)d_in[10];
  const float* b1 = (const float*)d_in[11];
  const float* W2 = (const float*)d_in[12];
  const float* b2 = (const float*)d_in[13];
  const float* W3 = (const float*)d_in[14];
  const float* b3 = (const float*)d_in[15];
  float* out = (float*)d_out;
  h16* state = (h16*)d_ws;  // B*N*DV fp16 = 64 MiB

  dkvmn_fused<<<dim3(B_), dim3(NTB), 0, stream>>>(
      concepts, interactions, Kmem, Vmem, cemb, iemb, We, be, Wa, ba,
      W1, b1, W2, b2, W3, b3, out, state);
}